// Round 6
// baseline (102.453 us; speedup 1.0000x reference)
//
#include <hip/hip_runtime.h>
#include <math.h>

#define BS 8
#define NR 60
#define NRP 30                // rotation pairs per batch
#define NP 500
#define NHW 6400
#define NPAIR (BS*NR)         // 480 (b,r) pairs
#define NBLK (BS*NRP)         // 240 blocks, one per (b, rot-pair)
#define NT_ELEMS (BS*NP*3)    // 12000
#define LT_PER_BLK 50         // 240*50 = 12000

#define BIGF 3.4e38f

__global__ __launch_bounds__(256) void main_kernel(
    const float* __restrict__ pred_t,        // (8,500,3)
    const float* __restrict__ pred_r,        // (8,60,4)
    const float* __restrict__ target_r,      // (8,1,500,3)
    const float* __restrict__ target_t,      // (8,3,6400)
    const float* __restrict__ model_points,  // (8,1,500,3)
    const int*   __restrict__ choose,        // (8,500)
    const float* __restrict__ rot_anchors,   // (60,4)
    float* __restrict__ out_sym,             // 480 (indexed by pair)
    float* __restrict__ out_non,             // 480
    float* __restrict__ out_reg,             // 480
    float* __restrict__ out_lt)              // 240 (per block)
{
    const int bid = blockIdx.x;
    const int b  = bid / NRP;
    const int rp = bid % NRP;
    const int r0 = 2 * rp, r1 = 2 * rp + 1;
    const int pair0 = b * NR + r0;           // pair1 = pair0 + 1
    const int tid = threadIdx.x;

    __shared__ float4 t4s[NP];               // {x,y,z,|t|^2} — 8000 B
    __shared__ float red[16];

    // --- stage target points global -> LDS, fusing |t|^2 ---
    for (int i = tid; i < NP; i += 256) {
        const float* p = target_r + (b * NP + i) * 3;
        float x = p[0], y = p[1], z = p[2];
        t4s[i] = make_float4(x, y, z, x * x + y * y + z * z);
    }

    // --- two quaternions -> rotation matrices ---
    const float* q0p = pred_r + pair0 * 4;
    const float w0 = q0p[0], x0 = q0p[1], y0 = q0p[2], z0 = q0p[3];
    const float w1 = q0p[4], x1 = q0p[5], y1 = q0p[6], z1 = q0p[7];

    const float A00 = 1.f - 2.f * (y0 * y0 + z0 * z0);
    const float A01 = 2.f * x0 * y0 - 2.f * w0 * z0;
    const float A02 = 2.f * w0 * y0 + 2.f * x0 * z0;
    const float A10 = 2.f * x0 * y0 + 2.f * z0 * w0;
    const float A11 = 1.f - 2.f * (x0 * x0 + z0 * z0);
    const float A12 = -2.f * w0 * x0 + 2.f * y0 * z0;
    const float A20 = -2.f * w0 * y0 + 2.f * x0 * z0;
    const float A21 = 2.f * w0 * x0 + 2.f * y0 * z0;
    const float A22 = 1.f - 2.f * (x0 * x0 + y0 * y0);

    const float B00 = 1.f - 2.f * (y1 * y1 + z1 * z1);
    const float B01 = 2.f * x1 * y1 - 2.f * w1 * z1;
    const float B02 = 2.f * w1 * y1 + 2.f * x1 * z1;
    const float B10 = 2.f * x1 * y1 + 2.f * z1 * w1;
    const float B11 = 1.f - 2.f * (x1 * x1 + z1 * z1);
    const float B12 = -2.f * w1 * x1 + 2.f * y1 * z1;
    const float B20 = -2.f * w1 * y1 + 2.f * x1 * z1;
    const float B21 = 2.f * w1 * x1 + 2.f * y1 * z1;
    const float B22 = 1.f - 2.f * (x1 * x1 + y1 * y1);

    // --- loss_t partial: 50 scattered elements per block (wave 0) ---
    float lt = 0.f;
    if (tid < LT_PER_BLK) {
        int e = bid * LT_PER_BLK + tid;      // flat index into pred_t (8,500,3)
        int bb = e / 1500;
        int rem = e - bb * 1500;
        int n = rem / 3;
        int k = rem - n * 3;
        int pos = choose[bb * NP + n];
        float ts = target_t[(bb * 3 + k) * NHW + pos];
        float diff = pred_t[e] - ts;
        float ad = fabsf(diff);
        lt = (ad < 1.f) ? 0.5f * diff * diff : ad - 0.5f;
    }

    // --- reg term: wave 0 handles r0, wave 1 handles r1 ---
    if (tid < 64) {
        float dot = -BIGF;
        if (tid < NR) {
            const float* an = rot_anchors + tid * 4;
            dot = w0 * an[0] + x0 * an[1] + y0 * an[2] + z0 * an[3];
        }
        float diag = __shfl(dot, r0, 64);
        float mx = dot;
        for (int o = 32; o > 0; o >>= 1) mx = fmaxf(mx, __shfl_down(mx, o, 64));
        for (int o = 32; o > 0; o >>= 1) lt += __shfl_down(lt, o, 64);
        if (tid == 0) {
            float rg = mx - diag;
            out_reg[pair0] = (rg > 0.001f) ? rg : 0.f;
            out_lt[bid] = lt;
        }
    } else if (tid < 128) {
        int ln = tid - 64;
        float dot = -BIGF;
        if (ln < NR) {
            const float* an = rot_anchors + ln * 4;
            dot = w1 * an[0] + x1 * an[1] + y1 * an[2] + z1 * an[3];
        }
        float diag = __shfl(dot, r1, 64);
        float mx = dot;
        for (int o = 32; o > 0; o >>= 1) mx = fmaxf(mx, __shfl_down(mx, o, 64));
        if (ln == 0) {
            float rg = mx - diag;
            out_reg[pair0 + 1] = (rg > 0.001f) ? rg : 0.f;
        }
    }

    // --- chamfer: 2 model points x 2 rotations per thread ---
    const int n0 = tid;
    const int n1 = tid + 256;
    const bool has1 = (n1 < NP);
    const int nc = has1 ? n1 : 0;

    const float* mpb = model_points + b * NP * 3;
    const float m0x = mpb[n0 * 3 + 0], m0y = mpb[n0 * 3 + 1], m0z = mpb[n0 * 3 + 2];
    const float m1x = mpb[nc * 3 + 0], m1y = mpb[nc * 3 + 1], m1z = mpb[nc * 3 + 2];

    // p[rot][pt]
    const float pA0x = A00 * m0x + A01 * m0y + A02 * m0z;
    const float pA0y = A10 * m0x + A11 * m0y + A12 * m0z;
    const float pA0z = A20 * m0x + A21 * m0y + A22 * m0z;
    const float pA1x = A00 * m1x + A01 * m1y + A02 * m1z;
    const float pA1y = A10 * m1x + A11 * m1y + A12 * m1z;
    const float pA1z = A20 * m1x + A21 * m1y + A22 * m1z;
    const float pB0x = B00 * m0x + B01 * m0y + B02 * m0z;
    const float pB0y = B10 * m0x + B11 * m0y + B12 * m0z;
    const float pB0z = B20 * m0x + B21 * m0y + B22 * m0z;
    const float pB1x = B00 * m1x + B01 * m1y + B02 * m1z;
    const float pB1y = B10 * m1x + B11 * m1y + B12 * m1z;
    const float pB1z = B20 * m1x + B21 * m1y + B22 * m1z;

    const float a2A0 = pA0x * pA0x + pA0y * pA0y + pA0z * pA0z;
    const float a2A1 = pA1x * pA1x + pA1y * pA1y + pA1z * pA1z;
    const float a2B0 = pB0x * pB0x + pB0y * pB0y + pB0z * pB0z;
    const float a2B1 = pB1x * pB1x + pB1y * pB1y + pB1z * pB1z;

    __syncthreads();                          // t4s ready

    // Hot loop: 1 uniform ds_read_b128 amortized over 4 dot products
    // (2 rotations x 2 model points). In-order DS + lgkmcnt(N) lets the
    // compiler pipeline the reads; 4 independent min accumulator sets.
    float mnA0 = BIGF, mnA1 = BIGF, mnB0 = BIGF, mnB1 = BIGF;
#pragma unroll 4
    for (int m = 0; m < NP; ++m) {
        float4 t = t4s[m];
        float dA0 = fmaf(pA0x, t.x, fmaf(pA0y, t.y, pA0z * t.z));
        float dA1 = fmaf(pA1x, t.x, fmaf(pA1y, t.y, pA1z * t.z));
        float dB0 = fmaf(pB0x, t.x, fmaf(pB0y, t.y, pB0z * t.z));
        float dB1 = fmaf(pB1x, t.x, fmaf(pB1y, t.y, pB1z * t.z));
        mnA0 = fminf(mnA0, fmaf(-2.f, dA0, t.w));
        mnA1 = fminf(mnA1, fmaf(-2.f, dA1, t.w));
        mnB0 = fminf(mnB0, fmaf(-2.f, dB0, t.w));
        mnB1 = fminf(mnB1, fmaf(-2.f, dB1, t.w));
    }

    // --- epilogue: sqrt terms per rotation ---
    float t0x, t0y, t0z, t1x, t1y, t1z;
    { float4 t = t4s[n0]; t0x = t.x; t0y = t.y; t0z = t.z; }
    { float4 t = t4s[nc]; t1x = t.x; t1y = t.y; t1z = t.z; }

    float symA = sqrtf(fmaxf(a2A0 + mnA0, 1e-12f));
    float symB = sqrtf(fmaxf(a2B0 + mnB0, 1e-12f));
    float dxA = pA0x - t0x, dyA = pA0y - t0y, dzA = pA0z - t0z;
    float dxB = pB0x - t0x, dyB = pB0y - t0y, dzB = pB0z - t0z;
    float nonA = sqrtf(dxA * dxA + dyA * dyA + dzA * dzA);
    float nonB = sqrtf(dxB * dxB + dyB * dyB + dzB * dzB);
    if (has1) {
        symA += sqrtf(fmaxf(a2A1 + mnA1, 1e-12f));
        symB += sqrtf(fmaxf(a2B1 + mnB1, 1e-12f));
        float ex = pA1x - t1x, ey = pA1y - t1y, ez = pA1z - t1z;
        nonA += sqrtf(ex * ex + ey * ey + ez * ez);
        float fx = pB1x - t1x, fy = pB1y - t1y, fz = pB1z - t1z;
        nonB += sqrtf(fx * fx + fy * fy + fz * fz);
    }

    // --- block reduce (4 waves x 4 values) ---
    for (int o = 32; o > 0; o >>= 1) {
        symA += __shfl_down(symA, o, 64);
        symB += __shfl_down(symB, o, 64);
        nonA += __shfl_down(nonA, o, 64);
        nonB += __shfl_down(nonB, o, 64);
    }
    const int wv = tid >> 6, ln = tid & 63;
    if (ln == 0) {
        red[wv] = symA; red[4 + wv] = symB;
        red[8 + wv] = nonA; red[12 + wv] = nonB;
    }
    __syncthreads();
    if (tid == 0) {
        out_sym[pair0]     = red[0] + red[1] + red[2] + red[3];
        out_sym[pair0 + 1] = red[4] + red[5] + red[6] + red[7];
        out_non[pair0]     = red[8] + red[9] + red[10] + red[11];
        out_non[pair0 + 1] = red[12] + red[13] + red[14] + red[15];
    }
}

__global__ __launch_bounds__(256) void finalize_kernel(
    const float* __restrict__ out_sym, const float* __restrict__ out_non,
    const float* __restrict__ out_reg, const float* __restrict__ out_lt,
    const float* __restrict__ pred_c,
    const unsigned char* __restrict__ symU8, const int* __restrict__ symI,
    const float* __restrict__ diam, float* __restrict__ out)
{
    const int tid = threadIdx.x;
    float s_r = 0.f, s_reg = 0.f, s_t = 0.f;
    for (int i = tid; i < NPAIR; i += 256) {
        int b = i / NR;
        // layout-agnostic bool read: true under both 1-byte-bool and int32 storage
        bool sym = (symU8[b] != 0) || (symI[b] != 0);
        float sum = sym ? out_sym[i] : out_non[i];
        float d = sum * (1.0f / NP);
        float c = pred_c[i];
        s_r += (d / (diam[b] * c) + logf(c)) * (1.0f / NR);
        s_reg += out_reg[i];
        if (i < NBLK) s_t += out_lt[i];
    }
    __shared__ float red[12];
    for (int o = 32; o > 0; o >>= 1) {
        s_r += __shfl_down(s_r, o, 64);
        s_reg += __shfl_down(s_reg, o, 64);
        s_t += __shfl_down(s_t, o, 64);
    }
    const int wv = tid >> 6, ln = tid & 63;
    if (ln == 0) { red[wv] = s_r; red[4 + wv] = s_reg; red[8 + wv] = s_t; }
    __syncthreads();
    if (tid == 0) {
        float lr = red[0] + red[1] + red[2] + red[3];
        float lreg = (red[4] + red[5] + red[6] + red[7]) * (1.0f / NPAIR);
        float ltv = (red[8] + red[9] + red[10] + red[11]) * (1.0f / NT_ELEMS);
        out[0] = lr + 2.f * lreg + 5.f * ltv;
        out[1] = lr;
        out[2] = lreg;
        out[3] = ltv;
    }
}

extern "C" void kernel_launch(void* const* d_in, const int* in_sizes, int n_in,
                              void* d_out, int out_size, void* d_ws, size_t ws_size,
                              hipStream_t stream) {
    const float* pred_t       = (const float*)d_in[0];
    const float* pred_r       = (const float*)d_in[1];
    const float* pred_c       = (const float*)d_in[2];
    const float* target_r     = (const float*)d_in[3];
    const float* target_t     = (const float*)d_in[4];
    const float* model_points = (const float*)d_in[5];
    const int*   choose       = (const int*)d_in[6];
    const unsigned char* symU8 = (const unsigned char*)d_in[7];
    const int*   symI         = (const int*)d_in[7];
    const float* diam         = (const float*)d_in[8];
    const float* anchors      = (const float*)d_in[9];
    float* out = (float*)d_out;

    char* ws = (char*)d_ws;
    float* o_sym = (float*)ws;                        // 480 floats
    float* o_non = o_sym + NPAIR;                     // 480
    float* o_reg = o_non + NPAIR;                     // 480
    float* o_lt  = o_reg + NPAIR;                     // 240

    main_kernel<<<NBLK, 256, 0, stream>>>(pred_t, pred_r, target_r, target_t,
                                          model_points, choose, anchors,
                                          o_sym, o_non, o_reg, o_lt);
    finalize_kernel<<<1, 256, 0, stream>>>(o_sym, o_non, o_reg, o_lt,
                                           pred_c, symU8, symI, diam, out);
}

// Round 7
// 91.081 us; speedup vs baseline: 1.1249x; 1.1249x over previous
//
#include <hip/hip_runtime.h>
#include <math.h>

#define BS 8
#define NR 60
#define NRP 30                // rotation pairs per batch
#define NP 500
#define NHW 6400
#define NPAIR (BS*NR)         // 480 (b,r) pairs
#define NBLK (BS*NRP)         // 240 blocks, one per (b, rot-pair)
#define NT_ELEMS (BS*NP*3)    // 12000
#define LT_PER_BLK 50         // 240*50 = 12000

#define BIGF 3.4e38f

// 240 blocks x 512 threads. Block = (b, rotation-pair).
// Lane l owns points {l, l+64, ..., l+448} (8 slots) for both rotations;
// wave w processes only its m-eighth of the 500 targets (63 ds_reads/wave
// instead of 500 — DS-instruction count drops 8x vs the R3 structure).
// Partial mins combine 8-way via LDS (min is associative over m-chunks).
__global__ __launch_bounds__(512) void main_kernel(
    const float* __restrict__ pred_t,        // (8,500,3)
    const float* __restrict__ pred_r,        // (8,60,4)
    const float* __restrict__ target_r,      // (8,1,500,3)
    const float* __restrict__ target_t,      // (8,3,6400)
    const float* __restrict__ model_points,  // (8,1,500,3)
    const int*   __restrict__ choose,        // (8,500)
    const float* __restrict__ rot_anchors,   // (60,4)
    float* __restrict__ out_sym,             // 480 (indexed by pair)
    float* __restrict__ out_non,             // 480
    float* __restrict__ out_reg,             // 480
    float* __restrict__ out_lt)              // 240 (per block)
{
    const int bid = blockIdx.x;
    const int b  = bid / NRP;
    const int rp = bid % NRP;
    const int r0 = 2 * rp, r1 = 2 * rp + 1;
    const int pair0 = b * NR + r0;           // pair1 = pair0 + 1
    const int tid = threadIdx.x;
    const int wv = tid >> 6;                 // wave 0..7
    const int ln = tid & 63;                 // lane 0..63

    __shared__ float4 t4s[NP];               // {x,y,z,|t|^2} — 8000 B
    __shared__ float2 part2[8 * 8 * 64];     // [w][slot][lane]{rotA,rotB} — 32 KB

    // --- stage target points global -> LDS, fusing |t|^2 ---
    if (tid < NP) {
        const float* p = target_r + (b * NP + tid) * 3;
        float x = p[0], y = p[1], z = p[2];
        t4s[tid] = make_float4(x, y, z, x * x + y * y + z * z);
    }

    // --- two quaternions -> rotation matrices ---
    const float* q0p = pred_r + pair0 * 4;
    const float w0 = q0p[0], x0 = q0p[1], y0 = q0p[2], z0 = q0p[3];
    const float w1 = q0p[4], x1 = q0p[5], y1 = q0p[6], z1 = q0p[7];

    const float A00 = 1.f - 2.f * (y0 * y0 + z0 * z0);
    const float A01 = 2.f * x0 * y0 - 2.f * w0 * z0;
    const float A02 = 2.f * w0 * y0 + 2.f * x0 * z0;
    const float A10 = 2.f * x0 * y0 + 2.f * z0 * w0;
    const float A11 = 1.f - 2.f * (x0 * x0 + z0 * z0);
    const float A12 = -2.f * w0 * x0 + 2.f * y0 * z0;
    const float A20 = -2.f * w0 * y0 + 2.f * x0 * z0;
    const float A21 = 2.f * w0 * x0 + 2.f * y0 * z0;
    const float A22 = 1.f - 2.f * (x0 * x0 + y0 * y0);

    const float B00 = 1.f - 2.f * (y1 * y1 + z1 * z1);
    const float B01 = 2.f * x1 * y1 - 2.f * w1 * z1;
    const float B02 = 2.f * w1 * y1 + 2.f * x1 * z1;
    const float B10 = 2.f * x1 * y1 + 2.f * z1 * w1;
    const float B11 = 1.f - 2.f * (x1 * x1 + z1 * z1);
    const float B12 = -2.f * w1 * x1 + 2.f * y1 * z1;
    const float B20 = -2.f * w1 * y1 + 2.f * x1 * z1;
    const float B21 = 2.f * w1 * x1 + 2.f * y1 * z1;
    const float B22 = 1.f - 2.f * (x1 * x1 + y1 * y1);

    // --- loss_t partial: 50 scattered elements per block (wave 0) ---
    float lt = 0.f;
    if (tid < LT_PER_BLK) {
        int e = bid * LT_PER_BLK + tid;      // flat index into pred_t (8,500,3)
        int bb = e / 1500;
        int rem = e - bb * 1500;
        int n = rem / 3;
        int k = rem - n * 3;
        int pos = choose[bb * NP + n];
        float ts = target_t[(bb * 3 + k) * NHW + pos];
        float diff = pred_t[e] - ts;
        float ad = fabsf(diff);
        lt = (ad < 1.f) ? 0.5f * diff * diff : ad - 0.5f;
    }

    // --- reg term: wave 0 handles r0 (+lt reduce), wave 1 handles r1 ---
    if (tid < 64) {
        float dot = -BIGF;
        if (tid < NR) {
            const float* an = rot_anchors + tid * 4;
            dot = w0 * an[0] + x0 * an[1] + y0 * an[2] + z0 * an[3];
        }
        float diag = __shfl(dot, r0, 64);
        float mx = dot;
        for (int o = 32; o > 0; o >>= 1) mx = fmaxf(mx, __shfl_down(mx, o, 64));
        for (int o = 32; o > 0; o >>= 1) lt += __shfl_down(lt, o, 64);
        if (tid == 0) {
            float rg = mx - diag;
            out_reg[pair0] = (rg > 0.001f) ? rg : 0.f;
            out_lt[bid] = lt;
        }
    } else if (tid < 128) {
        float dot = -BIGF;
        if (ln < NR) {
            const float* an = rot_anchors + ln * 4;
            dot = w1 * an[0] + x1 * an[1] + y1 * an[2] + z1 * an[3];
        }
        float diag = __shfl(dot, r1, 64);
        float mx = dot;
        for (int o = 32; o > 0; o >>= 1) mx = fmaxf(mx, __shfl_down(mx, o, 64));
        if (ln == 0) {
            float rg = mx - diag;
            out_reg[pair0 + 1] = (rg > 0.001f) ? rg : 0.f;
        }
    }

    // --- rotate the 8 owned model points for both rotations; keep -2*p ---
    // (p recovered in epilogue as -0.5 * n; a2 = |p|^2 recomputed there)
    float nAx[8], nAy[8], nAz[8], nBx[8], nBy[8], nBz[8];
    const float* mpb = model_points + b * NP * 3;
#pragma unroll
    for (int k = 0; k < 8; ++k) {
        int pt = k * 64 + ln;
        int pc = (pt < NP) ? pt : 0;         // clamp; masked at combine
        float mx_ = mpb[pc * 3 + 0], my_ = mpb[pc * 3 + 1], mz_ = mpb[pc * 3 + 2];
        float pax = A00 * mx_ + A01 * my_ + A02 * mz_;
        float pay = A10 * mx_ + A11 * my_ + A12 * mz_;
        float paz = A20 * mx_ + A21 * my_ + A22 * mz_;
        float pbx = B00 * mx_ + B01 * my_ + B02 * mz_;
        float pby = B10 * mx_ + B11 * my_ + B12 * mz_;
        float pbz = B20 * mx_ + B21 * my_ + B22 * mz_;
        nAx[k] = -2.f * pax; nAy[k] = -2.f * pay; nAz[k] = -2.f * paz;
        nBx[k] = -2.f * pbx; nBy[k] = -2.f * pby; nBz[k] = -2.f * pbz;
    }

    __syncthreads();                          // t4s ready

    // --- main loop: this wave's m-eighth only ---
    const int mstart = (wv * NP) >> 3;
    const int mend   = ((wv + 1) * NP) >> 3;
    float mnA[8], mnB[8];
#pragma unroll
    for (int k = 0; k < 8; ++k) { mnA[k] = BIGF; mnB[k] = BIGF; }

    for (int m = mstart; m < mend; ++m) {
        float4 t = t4s[m];                    // wave-uniform -> broadcast
#pragma unroll
        for (int k = 0; k < 8; ++k) {
            // d2 - |p|^2 = t.w - 2*p.t  (|p|^2 added back in epilogue)
            float dA = fmaf(nAx[k], t.x, fmaf(nAy[k], t.y, fmaf(nAz[k], t.z, t.w)));
            mnA[k] = fminf(mnA[k], dA);
            float dB = fmaf(nBx[k], t.x, fmaf(nBy[k], t.y, fmaf(nBz[k], t.z, t.w)));
            mnB[k] = fminf(mnB[k], dB);
        }
    }

    // --- publish partial mins ---
#pragma unroll
    for (int k = 0; k < 8; ++k)
        part2[(wv * 8 + k) * 64 + ln] = make_float2(mnA[k], mnB[k]);
    __syncthreads();

    // --- combine: wave 0 -> rotation A, wave 1 -> rotation B ---
    if (wv < 2) {
        const float* partf = (const float*)part2;
        float symsum = 0.f, nonsum = 0.f;
#pragma unroll
        for (int k = 0; k < 8; ++k) {
            float mn = BIGF;
#pragma unroll
            for (int w2 = 0; w2 < 8; ++w2) {
                float v = partf[((w2 * 8 + k) * 64 + ln) * 2 + wv];  // 2-way stride: free
                mn = fminf(mn, v);
            }
            float px = -0.5f * ((wv == 0) ? nAx[k] : nBx[k]);
            float py = -0.5f * ((wv == 0) ? nAy[k] : nBy[k]);
            float pz = -0.5f * ((wv == 0) ? nAz[k] : nBz[k]);
            float a2 = px * px + py * py + pz * pz;
            int pt = k * 64 + ln;
            if (pt < NP) {
                float d2 = fmaxf(a2 + mn, 1e-12f);
                symsum += sqrtf(d2);
                float4 t = t4s[pt];
                float dx = px - t.x, dy = py - t.y, dz = pz - t.z;
                nonsum += sqrtf(dx * dx + dy * dy + dz * dz);
            }
        }
        for (int o = 32; o > 0; o >>= 1) {
            symsum += __shfl_down(symsum, o, 64);
            nonsum += __shfl_down(nonsum, o, 64);
        }
        if (ln == 0) {
            out_sym[pair0 + wv] = symsum;
            out_non[pair0 + wv] = nonsum;
        }
    }
}

__global__ __launch_bounds__(256) void finalize_kernel(
    const float* __restrict__ out_sym, const float* __restrict__ out_non,
    const float* __restrict__ out_reg, const float* __restrict__ out_lt,
    const float* __restrict__ pred_c,
    const unsigned char* __restrict__ symU8, const int* __restrict__ symI,
    const float* __restrict__ diam, float* __restrict__ out)
{
    const int tid = threadIdx.x;
    float s_r = 0.f, s_reg = 0.f, s_t = 0.f;
    for (int i = tid; i < NPAIR; i += 256) {
        int b = i / NR;
        // layout-agnostic bool read: true under both 1-byte-bool and int32 storage
        bool sym = (symU8[b] != 0) || (symI[b] != 0);
        float sum = sym ? out_sym[i] : out_non[i];
        float d = sum * (1.0f / NP);
        float c = pred_c[i];
        s_r += (d / (diam[b] * c) + logf(c)) * (1.0f / NR);
        s_reg += out_reg[i];
        if (i < NBLK) s_t += out_lt[i];
    }
    __shared__ float red[12];
    for (int o = 32; o > 0; o >>= 1) {
        s_r += __shfl_down(s_r, o, 64);
        s_reg += __shfl_down(s_reg, o, 64);
        s_t += __shfl_down(s_t, o, 64);
    }
    const int wv = tid >> 6, ln = tid & 63;
    if (ln == 0) { red[wv] = s_r; red[4 + wv] = s_reg; red[8 + wv] = s_t; }
    __syncthreads();
    if (tid == 0) {
        float lr = red[0] + red[1] + red[2] + red[3];
        float lreg = (red[4] + red[5] + red[6] + red[7]) * (1.0f / NPAIR);
        float ltv = (red[8] + red[9] + red[10] + red[11]) * (1.0f / NT_ELEMS);
        out[0] = lr + 2.f * lreg + 5.f * ltv;
        out[1] = lr;
        out[2] = lreg;
        out[3] = ltv;
    }
}

extern "C" void kernel_launch(void* const* d_in, const int* in_sizes, int n_in,
                              void* d_out, int out_size, void* d_ws, size_t ws_size,
                              hipStream_t stream) {
    const float* pred_t       = (const float*)d_in[0];
    const float* pred_r       = (const float*)d_in[1];
    const float* pred_c       = (const float*)d_in[2];
    const float* target_r     = (const float*)d_in[3];
    const float* target_t     = (const float*)d_in[4];
    const float* model_points = (const float*)d_in[5];
    const int*   choose       = (const int*)d_in[6];
    const unsigned char* symU8 = (const unsigned char*)d_in[7];
    const int*   symI         = (const int*)d_in[7];
    const float* diam         = (const float*)d_in[8];
    const float* anchors      = (const float*)d_in[9];
    float* out = (float*)d_out;

    char* ws = (char*)d_ws;
    float* o_sym = (float*)ws;                        // 480 floats
    float* o_non = o_sym + NPAIR;                     // 480
    float* o_reg = o_non + NPAIR;                     // 480
    float* o_lt  = o_reg + NPAIR;                     // 240

    main_kernel<<<NBLK, 512, 0, stream>>>(pred_t, pred_r, target_r, target_t,
                                          model_points, choose, anchors,
                                          o_sym, o_non, o_reg, o_lt);
    finalize_kernel<<<1, 256, 0, stream>>>(o_sym, o_non, o_reg, o_lt,
                                           pred_c, symU8, symI, diam, out);
}